// Round 8
// baseline (306.533 us; speedup 1.0000x reference)
//
#include <hip/hip_runtime.h>
#include <stdint.h>

// BinaryConv2d: out = conv2d(x, sign(w), pad=1) + sign(bias)
// x: [32,256,56,56] f32, w: [256,256,3,3] f32, bias: [256] f32, out: [32,256,56,56] f32
//
// Round 14: A-LDS pipeline DELETED. wq (576 KB) is L2-resident, so A fragments are loaded
// directly from global per tap (1 KB fully-coalesced dwordx4 per wave per mt, prefetched
// one tap ahead under the MFMAs). Removes As dbuf + DMA + 8 of 16 barriers per block;
// LDS drops 77->28 KB; waves drift through the 9-tap loop (no lockstep). wq layout now
// plain [s][o][c] (the k-chunk permutation existed only for A-LDS bank conflicts).
//   K1 prep_combo: 16 blocks weight binarize (plain) || 1024 blocks amax partials
//   K2 bconv_fx4:  fused conv; preamble reduces partials; B-halo quantized on the fly.

#define N_IMG 32
#define C_IN  256
#define H_IN  56
#define W_IN  56
#define O_OUT 256
#define HW    (H_IN * W_IN)      // 3136
#define K_RAW (C_IN * 9)         // 2304

typedef int8_t i8x16 __attribute__((ext_vector_type(16)));
typedef int    i32x4 __attribute__((ext_vector_type(4)));
typedef float  f32x4 __attribute__((ext_vector_type(4)));
typedef float  f32x4u __attribute__((ext_vector_type(4), aligned(4)));  // 4B-aligned vec load
typedef __bf16 bf16x8 __attribute__((ext_vector_type(8)));   // fallback only

// wq layout: [s=cc*9+tap][o256][c64] i8, PLAIN (no permutation)
#define WQ_BYTES ((size_t)36 * 256 * 64)             // 589,824
#define ARR_OFF  WQ_BYTES
#define WS_NEED  (ARR_OFF + 4096)

#define BPITCH  80               // LDS bytes per pixel row (64 data + 16 pad)
#define BS_ROWB (58 * BPITCH)    // 4640 B per halo row

#define AMAX_BLOCKS 1024

// ---- prep_combo: blocks 0..15 = weight binarize; blocks 16.. = amax partials ----
__global__ void prep_combo(const float* __restrict__ x, const float* __restrict__ w,
                           int8_t* __restrict__ wq, float* __restrict__ am_arr) {
    __shared__ __attribute__((aligned(16))) int8_t S[9 * 64 * 64];   // 36864
    const int bx = blockIdx.x;
    const int t  = threadIdx.x;

    if (bx >= 16) {
        // ---- absmax partial: per-block max, plain store (no atomic, no init) ----
        const int b = bx - 16;                 // 0..1023
        const size_t NV = (size_t)N_IMG * C_IN * HW / 4;
        float m = 0.f;
        for (size_t i = (size_t)b * 256 + t; i < NV; i += (size_t)AMAX_BLOCKS * 256) {
            f32x4 v = ((const f32x4*)x)[i];
            m = fmaxf(m, fmaxf(fmaxf(fabsf(v[0]), fabsf(v[1])),
                               fmaxf(fabsf(v[2]), fabsf(v[3]))));
        }
#pragma unroll
        for (int off = 32; off; off >>= 1)
            m = fmaxf(m, __shfl_down(m, off));
        float* red = (float*)S;
        if ((t & 63) == 0) red[t >> 6] = m;
        __syncthreads();
        if (t == 0)
            am_arr[b] = fmaxf(fmaxf(red[0], red[1]), fmaxf(red[2], red[3]));
        return;
    }

    // ---- weight binarize, coalesced via LDS transpose, plain [s][o][c] output ----
    const int og = bx >> 2;          // o-group: o0 = og*64
    const int cc = bx & 3;
    const int o0 = og * 64;
#pragma unroll
    for (int kk = 0; kk < 4; ++kk) {
        const int p   = kk * 256 + t;        // 0..1023 = (o_l, chg)
        const int o_l = p >> 4;              // 0..63
        const int chg = p & 15;              // 4 channels each
        const float* src = w + (size_t)(o0 + o_l) * K_RAW + (size_t)(cc * 64 + chg * 4) * 9;
        f32x4u v[9];
#pragma unroll
        for (int q = 0; q < 9; ++q) v[q] = *(const f32x4u*)(src + q * 4);
#pragma unroll
        for (int tap = 0; tap < 9; ++tap) {
            unsigned dw = 0;
#pragma unroll
            for (int co = 0; co < 4; ++co) {
                const int flat = co * 9 + tap;           // static index
                const float fv = v[flat >> 2][flat & 3];
                dw |= (unsigned)((fv >= 0.f) ? 0x01u : 0xffu) << (co * 8);
            }
            *(unsigned*)&S[tap * 4096 + o_l * 64 + chg * 4] = dw;
        }
    }
    __syncthreads();
#pragma unroll
    for (int kk = 0; kk < 9; ++kk) {
        const int c    = kk * 256 + t;       // 0..2303 chunks of 16 B
        const int tap  = c >> 8;
        const int rem  = c & 255;
        const int o_l  = rem >> 2;
        const int cpos = rem & 3;
        i32x4 vv = *(const i32x4*)&S[tap * 4096 + o_l * 64 + cpos * 16];
        *(i32x4*)(wq + ((size_t)(cc * 9 + tap) * 256 + (o0 + o_l)) * 64 + cpos * 16) = vv;
    }
}

// ---- main: block = 128 o x 224 px (4 out rows x 56); A direct-from-L2, B fused-quantized ----
__launch_bounds__(256, 2)
__global__ void bconv_fx4(const float* __restrict__ x,
                          const int8_t* __restrict__ wq,
                          const float* __restrict__ bias,
                          const float* __restrict__ am_arr,
                          float* __restrict__ out) {
    __shared__ __attribute__((aligned(16))) int8_t Bs[6 * BS_ROWB];  // 27840 B halo
    __shared__ float sred[4];

    const int tid  = threadIdx.x;
    const int lane = tid & 63;
    const int wv   = tid >> 6;
    const int row  = lane & 15;
    const int quad = lane >> 4;

    const int nrp  = blockIdx.x;              // 0..447
    const int n    = nrp / 14;
    const int rp   = nrp - n * 14;
    const int oblk = blockIdx.y;              // 0..1
    const int h0   = rp * 4;

    // ---- preamble: reduce 1024 amax partials (4 KB, L2-broadcast) -> scale/inv ----
    float m = fmaxf(fmaxf(am_arr[tid], am_arr[tid + 256]),
                    fmaxf(am_arr[tid + 512], am_arr[tid + 768]));
#pragma unroll
    for (int off = 32; off; off >>= 1)
        m = fmaxf(m, __shfl_down(m, off));
    if (lane == 0) sred[wv] = m;
    __syncthreads();
    m = fmaxf(fmaxf(sred[0], sred[1]), fmaxf(sred[2], sred[3]));
    const float scale = 127.f / fmaxf(m, 1e-20f);
    const float inv   = m * (1.0f / 127.0f);

    // B-stage thread mapping: wg = pixel group = tid>>4, cg = ch group = tid&15.
    // ds_write bank = 16*(wg&1)+cg+const -> 32 banks x 2 lanes = conflict-free (R13).
    const int wg = tid >> 4;
    const int cg = tid & 15;

    int pr[4], pc[4];
    bool live[4];
#pragma unroll
    for (int nt = 0; nt < 4; ++nt) {
        int p = wv * 64 + nt * 16 + row;
        live[nt] = (p < 224);
        int r = p / 56;
        int c = p - r * 56;
        if (!live[nt]) { r = 0; c = 0; }
        pr[nt] = r;
        pc[nt] = c;
    }

    i32x4 acc[8][4];
#pragma unroll
    for (int mt = 0; mt < 8; ++mt)
#pragma unroll
        for (int nt = 0; nt < 4; ++nt)
            acc[mt][nt] = (i32x4){0, 0, 0, 0};

    // A-read lane address (plain layout): fragment (o = mt*16+row, k-chunk quad)
    // per wave per mt: 64 lanes x 16 B = one coalesced 1 KB dwordx4 from L2-resident wq.
    const int8_t* Aln = wq + (size_t)oblk * 8192 + row * 64 + quad * 16;
    int addrB[4];
#pragma unroll
    for (int nt = 0; nt < 4; ++nt)
        addrB[nt] = pr[nt] * BS_ROWB + pc[nt] * BPITCH + quad * 16;

    i32x4 af[8], bc[4], bn[4];

    for (int cc = 0; cc < 4; ++cc) {
        __syncthreads();   // closes prev-cc Bs readers

        // ---- stage B halo for this cc directly from x, quantizing on the fly ----
        {
            const float* xpl = x + ((size_t)n * C_IN + cc * 64 + cg * 4) * HW;
#pragma unroll 2
            for (int r6 = 0; r6 < 6; ++r6) {
                const int hin = h0 + r6 - 1;            // input row, -1..56
                int8_t* lrow = &Bs[r6 * BS_ROWB];
                if (wg >= 14) {                          // border cols ww=0 / ww=57
                    const int ww = (wg == 14) ? 0 : 57;
                    *(int*)(lrow + ww * BPITCH + cg * 4) = 0;
                } else if ((unsigned)hin < 56u) {
                    const float* src = xpl + (size_t)hin * W_IN + wg * 4;
                    f32x4 v0 = *(const f32x4*)(src);
                    f32x4 v1 = *(const f32x4*)(src + HW);
                    f32x4 v2 = *(const f32x4*)(src + 2 * HW);
                    f32x4 v3 = *(const f32x4*)(src + 3 * HW);
#pragma unroll
                    for (int k = 0; k < 4; ++k) {
                        float f0 = fminf(fmaxf(v0[k] * scale, -127.f), 127.f);
                        float f1 = fminf(fmaxf(v1[k] * scale, -127.f), 127.f);
                        float f2 = fminf(fmaxf(v2[k] * scale, -127.f), 127.f);
                        float f3 = fminf(fmaxf(v3[k] * scale, -127.f), 127.f);
                        int d = ((int)(uint8_t)(int8_t)(int)rintf(f0))
                              | ((int)(uint8_t)(int8_t)(int)rintf(f1) << 8)
                              | ((int)(uint8_t)(int8_t)(int)rintf(f2) << 16)
                              | ((int)(uint8_t)(int8_t)(int)rintf(f3) << 24);
                        *(int*)(lrow + (wg * 4 + k + 1) * BPITCH + cg * 4) = d;
                    }
                } else {                                 // padded row -> zeros
#pragma unroll
                    for (int k = 0; k < 4; ++k)
                        *(int*)(lrow + (wg * 4 + k + 1) * BPITCH + cg * 4) = 0;
                }
            }
        }
        __syncthreads();   // Bs visible; no other barriers until next cc

        // ---- 9 taps, software-pipelined: A from global (L2), B from LDS ----
        const int s0 = cc * 9;
        const int8_t* As0 = Aln + (size_t)s0 * 16384;
#pragma unroll
        for (int mt = 0; mt < 8; ++mt)
            af[mt] = *(const i32x4*)(As0 + mt * 1024);
#pragma unroll
        for (int nt = 0; nt < 4; ++nt)
            bc[nt] = *(const i32x4*)(&Bs[addrB[nt]]);

#pragma unroll
        for (int tap = 0; tap < 9; ++tap) {
            if (tap < 8) {
                const int offn = ((tap + 1) / 3) * BS_ROWB + ((tap + 1) % 3) * BPITCH;
#pragma unroll
                for (int nt = 0; nt < 4; ++nt)
                    bn[nt] = *(const i32x4*)(&Bs[addrB[nt] + offn]);
                const int8_t* Anx = Aln + (size_t)(s0 + tap + 1) * 16384;
#pragma unroll
                for (int mt = 0; mt < 8; ++mt) {
                    i32x4 a = af[mt];
#pragma unroll
                    for (int nt = 0; nt < 4; ++nt)
                        acc[mt][nt] = __builtin_amdgcn_mfma_i32_16x16x64_i8(
                            a, bc[nt], acc[mt][nt], 0, 0, 0);
                    af[mt] = *(const i32x4*)(Anx + mt * 1024);   // tap+1, hidden under MFMAs
                }
#pragma unroll
                for (int nt = 0; nt < 4; ++nt) bc[nt] = bn[nt];
            } else {
#pragma unroll
                for (int mt = 0; mt < 8; ++mt)
#pragma unroll
                    for (int nt = 0; nt < 4; ++nt)
                        acc[mt][nt] = __builtin_amdgcn_mfma_i32_16x16x64_i8(
                            af[mt], bc[nt], acc[mt][nt], 0, 0, 0);
            }
        }
    }

    // ---- epilogue, nt-inner: 4 x 64B consecutive stores per channel (write combining) ----
    float* base0 = out + ((size_t)n * O_OUT + oblk * 128) * HW;
    int pixoff[4];
#pragma unroll
    for (int nt = 0; nt < 4; ++nt)
        pixoff[nt] = (h0 + pr[nt]) * W_IN + pc[nt];
#pragma unroll
    for (int mt = 0; mt < 8; ++mt) {
        f32x4 bv = *(const f32x4*)(bias + oblk * 128 + mt * 16 + quad * 4);
#pragma unroll
        for (int r = 0; r < 4; ++r) {
            const float sb = (bv[r] >= 0.0f) ? 1.0f : -1.0f;
            const size_t ob = (size_t)(mt * 16 + quad * 4 + r) * HW;
#pragma unroll
            for (int nt = 0; nt < 4; ++nt)
                if (live[nt]) base0[ob + pixoff[nt]] = (float)acc[mt][nt][r] * inv + sb;
        }
    }
}

// ================= fallback (only if ws too small): fp32->bf16 direct =================
#define CHW (C_IN * HW)
#define FPITCH 40

__launch_bounds__(256, 2)
__global__ void bconv_fallback(const float* __restrict__ x,
                               const float* __restrict__ w,
                               const float* __restrict__ bias,
                               float* __restrict__ out) {
    __shared__ __attribute__((aligned(16))) __bf16 Asf[128 * FPITCH];
    __shared__ __attribute__((aligned(16))) __bf16 Bsf[128 * FPITCH];

    const int tid  = threadIdx.x;
    const int lane = tid & 63;
    const int wv   = tid >> 6;
    const int pblk = blockIdx.x;
    const int oblk = blockIdx.y;

    const int p_local = tid & 127;
    const int cgrp    = tid >> 7;
    const int pixel   = pblk * 128 + p_local;
    const int n_img   = pixel / HW;
    const int hw      = pixel - n_img * HW;
    const int h       = hw / W_IN;
    const int wx      = hw - h * W_IN;
    const float* xbase = x + (size_t)n_img * CHW;

    f32x4 acc[8][2];
#pragma unroll
    for (int mt = 0; mt < 8; ++mt)
#pragma unroll
        for (int nt = 0; nt < 2; ++nt)
            acc[mt][nt] = (f32x4){0.f, 0.f, 0.f, 0.f};

    const int pix_wave = wv * 32;
    const int row  = lane & 15;
    const int quad = lane >> 4;

    for (int tap = 0; tap < 9; ++tap) {
        const int dh = tap / 3 - 1;
        const int dw = tap % 3 - 1;
        const int hh = h + dh;
        const int ww = wx + dw;
        const bool valid = ((unsigned)hh < (unsigned)H_IN) && ((unsigned)ww < (unsigned)W_IN);
        const int offs = hh * W_IN + ww;

        for (int ck = 0; ck < 8; ++ck) {
            __syncthreads();
#pragma unroll
            for (int rep = 0; rep < 2; ++rep) {
                int v  = tid + rep * 256;
                int oa = v >> 2;
                int c8 = v & 3;
                const float* wsrc = w + (size_t)(oblk * 128 + oa) * K_RAW
                                      + (ck * 32 + c8 * 8) * 9 + tap;
                bf16x8 val;
#pragma unroll
                for (int j = 0; j < 8; ++j)
                    val[j] = (wsrc[j * 9] >= 0.0f) ? (__bf16)1.0f : (__bf16)(-1.0f);
                *(bf16x8*)(&Asf[oa * FPITCH + c8 * 8]) = val;
            }
            {
                const int cbase = (ck * 32 + cgrp * 16) * HW + offs;
#pragma unroll
                for (int g = 0; g < 2; ++g) {
                    bf16x8 vb;
#pragma unroll
                    for (int j = 0; j < 8; ++j) {
                        float f = valid ? xbase[cbase + (g * 8 + j) * HW] : 0.0f;
                        vb[j] = (__bf16)f;
                    }
                    *(bf16x8*)(&Bsf[p_local * FPITCH + cgrp * 16 + g * 8]) = vb;
                }
            }
            __syncthreads();
            bf16x8 bfrag[2];
#pragma unroll
            for (int nt = 0; nt < 2; ++nt)
                bfrag[nt] = *(const bf16x8*)(&Bsf[(pix_wave + nt * 16 + row) * FPITCH + quad * 8]);
#pragma unroll
            for (int mt = 0; mt < 8; ++mt) {
                bf16x8 afrag = *(const bf16x8*)(&Asf[(mt * 16 + row) * FPITCH + quad * 8]);
#pragma unroll
                for (int nt = 0; nt < 2; ++nt)
                    acc[mt][nt] = __builtin_amdgcn_mfma_f32_16x16x32_bf16(
                        afrag, bfrag[nt], acc[mt][nt], 0, 0, 0);
            }
        }
    }

#pragma unroll
    for (int nt = 0; nt < 2; ++nt) {
        int pix = pblk * 128 + pix_wave + nt * 16 + row;
        int ni  = pix / HW;
        int phw = pix - ni * HW;
        float* obase = out + (size_t)ni * (O_OUT * HW) + phw;
#pragma unroll
        for (int mt = 0; mt < 8; ++mt) {
            int o0 = oblk * 128 + mt * 16 + quad * 4;
#pragma unroll
            for (int r = 0; r < 4; ++r) {
                int o = o0 + r;
                float sb = (bias[o] >= 0.0f) ? 1.0f : -1.0f;
                obase[(size_t)o * HW] = acc[mt][nt][r] + sb;
            }
        }
    }
}

extern "C" void kernel_launch(void* const* d_in, const int* in_sizes, int n_in,
                              void* d_out, int out_size, void* d_ws, size_t ws_size,
                              hipStream_t stream) {
    const float* x    = (const float*)d_in[0];
    const float* w    = (const float*)d_in[1];
    const float* bias = (const float*)d_in[2];
    float* out        = (float*)d_out;

    if (ws_size >= WS_NEED) {
        int8_t* wq     = (int8_t*)d_ws;
        float*  am_arr = (float*)((char*)d_ws + ARR_OFF);

        prep_combo<<<dim3(16 + AMAX_BLOCKS), dim3(256), 0, stream>>>(x, w, wq, am_arr);
        bconv_fx4<<<dim3(N_IMG * 14, 2), dim3(256), 0, stream>>>(x, wq, bias, am_arr, out);
    } else {
        bconv_fallback<<<dim3((N_IMG * HW) / 128, 2), dim3(256), 0, stream>>>(
            x, w, bias, out);
    }
}

// Round 9
// 268.288 us; speedup vs baseline: 1.1426x; 1.1426x over previous
//
#include <hip/hip_runtime.h>
#include <stdint.h>

// BinaryConv2d: out = conv2d(x, sign(w), pad=1) + sign(bias)
// x: [32,256,56,56] f32, w: [256,256,3,3] f32, bias: [256] f32, out: [32,256,56,56] f32
//
// Round 15: revert to the verified best pipeline (R8/"271.6us" config: prep_combo ->
// xtrans_q -> bconv_i8 with i8-staged B, DMA'd A, 3-tap chunks) + ONE change:
// XCD-pairing block swizzle in bconv_i8. Grid is 1-D 896; launch id j maps so that
//  - the two oblk blocks of the same (n,rp) tile get ids 8 apart -> same XCD L2,
//    so the second one reads the 89KB xq halo from L2 instead of HBM;
//  - consecutive nrp stay on the same XCD -> rp-adjacent halo rows (3/6 shared) hit L2.
// (R14 lesson: A-from-L2 per tap regressed; LDS A-path + i8 B-path stay.)

#define N_IMG 32
#define C_IN  256
#define H_IN  56
#define W_IN  56
#define O_OUT 256
#define HW    (H_IN * W_IN)      // 3136
#define K_RAW (C_IN * 9)         // 2304

typedef int8_t i8x16 __attribute__((ext_vector_type(16)));
typedef int    i32x4 __attribute__((ext_vector_type(4)));
typedef float  f32x4 __attribute__((ext_vector_type(4)));
typedef float  f32x4u __attribute__((ext_vector_type(4), aligned(4)));  // 4B-aligned vec load
typedef __bf16 bf16x8 __attribute__((ext_vector_type(8)));   // fallback only

// xq layout: [n][cc4][hh58][ww58][c64] i8 (zero border)
#define XQ_WSTR (58 * 64)        // 3712 B per padded row
#define XQ_CSTR (58 * 58 * 64)   // 215296 B per (n,cc) plane
#define XQ_BYTES ((size_t)N_IMG * 4 * XQ_CSTR)       // 27,557,888
// wq layout: [s=cc*9+tap][o256][c64] i8, k-chunk permuted (see prep_combo)
#define WQ_BYTES ((size_t)36 * 256 * 64)             // 589,824
#define AM_OFF   (XQ_BYTES + WQ_BYTES)
#define ARR_OFF  (AM_OFF + 64)
#define WS_NEED  (ARR_OFF + 4096)

#define BPITCH  80               // LDS bytes per pixel row (64 data + 16 pad)
#define BS_ROWB (58 * BPITCH)    // 4640 B per halo row
#define CHUNK_B (3 * 8192)       // 24576 B: 3 taps of A per buffer

#define AMAX_BLOCKS 1024

#define AS1 __attribute__((address_space(1)))
#define AS3 __attribute__((address_space(3)))

__device__ __forceinline__ void dma16(const void* g, void* l) {
    __builtin_amdgcn_global_load_lds((const AS1 uint32_t*)g, (AS3 uint32_t*)l, 16, 0, 0);
}

// ---- prep_combo: blocks 0..15 = weight binarize/permute; blocks 16.. = amax partials ----
__global__ void prep_combo(const float* __restrict__ x, const float* __restrict__ w,
                           int8_t* __restrict__ wq, float* __restrict__ am_arr) {
    __shared__ __attribute__((aligned(16))) int8_t S[9 * 64 * 64];   // 36864
    const int bx = blockIdx.x;
    const int t  = threadIdx.x;

    if (bx >= 16) {
        // ---- absmax partial: per-block max, plain store (no atomic, no init) ----
        const int b = bx - 16;                 // 0..1023
        const size_t NV = (size_t)N_IMG * C_IN * HW / 4;
        float m = 0.f;
        for (size_t i = (size_t)b * 256 + t; i < NV; i += (size_t)AMAX_BLOCKS * 256) {
            f32x4 v = ((const f32x4*)x)[i];
            m = fmaxf(m, fmaxf(fmaxf(fabsf(v[0]), fabsf(v[1])),
                               fmaxf(fabsf(v[2]), fabsf(v[3]))));
        }
#pragma unroll
        for (int off = 32; off; off >>= 1)
            m = fmaxf(m, __shfl_down(m, off));
        float* red = (float*)S;
        if ((t & 63) == 0) red[t >> 6] = m;
        __syncthreads();
        if (t == 0)
            am_arr[b] = fmaxf(fmaxf(red[0], red[1]), fmaxf(red[2], red[3]));
        return;
    }

    // ---- weight binarize + k-chunk permutation, coalesced via LDS transpose ----
    // Position (s,o,cpos) stores TRUE k-chunk (cpos - ((o&15)>>1)) & 3 so the bconv A-read
    // at chunk (quad + (row>>1)) & 3 recovers chunk `quad` conflict-free at pitch 64.
    const int og = bx >> 2;          // o-group: o0 = og*64
    const int cc = bx & 3;
    const int o0 = og * 64;
#pragma unroll
    for (int kk = 0; kk < 4; ++kk) {
        const int p   = kk * 256 + t;        // 0..1023 = (o_l, chg)
        const int o_l = p >> 4;              // 0..63
        const int chg = p & 15;              // 4 channels each
        const float* src = w + (size_t)(o0 + o_l) * K_RAW + (size_t)(cc * 64 + chg * 4) * 9;
        f32x4u v[9];
#pragma unroll
        for (int q = 0; q < 9; ++q) v[q] = *(const f32x4u*)(src + q * 4);
#pragma unroll
        for (int tap = 0; tap < 9; ++tap) {
            unsigned dw = 0;
#pragma unroll
            for (int co = 0; co < 4; ++co) {
                const int flat = co * 9 + tap;           // static index
                const float fv = v[flat >> 2][flat & 3];
                dw |= (unsigned)((fv >= 0.f) ? 0x01u : 0xffu) << (co * 8);
            }
            *(unsigned*)&S[tap * 4096 + o_l * 64 + chg * 4] = dw;
        }
    }
    __syncthreads();
#pragma unroll
    for (int kk = 0; kk < 9; ++kk) {
        const int c    = kk * 256 + t;       // 0..2303 chunks of 16 B
        const int tap  = c >> 8;
        const int rem  = c & 255;
        const int o_l  = rem >> 2;
        const int cpos = rem & 3;
        const int truec = (cpos - ((o_l & 15) >> 1)) & 3;
        i32x4 vv = *(const i32x4*)&S[tap * 4096 + o_l * 64 + truec * 16];
        *(i32x4*)(wq + ((size_t)(cc * 9 + tap) * 256 + (o0 + o_l)) * 64 + cpos * 16) = vv;
    }
}

// ---- x quantize + transpose: NCHW f32 -> [n][cc4][hh][ww][c64] i8, zero border ----
// Reduces the 1024 amax partials inline (4 KB, L2-hot) -> scale; block (0,0,0) publishes *am.
__global__ void xtrans_q(const float* __restrict__ x, int8_t* __restrict__ xq,
                         const float* __restrict__ am_arr,
                         unsigned* __restrict__ am_bits) {
    __shared__ float red[4];
    const int t = threadIdx.x;
    float m = fmaxf(fmaxf(am_arr[t], am_arr[t + 256]),
                    fmaxf(am_arr[t + 512], am_arr[t + 768]));
#pragma unroll
    for (int off = 32; off; off >>= 1)
        m = fmaxf(m, __shfl_down(m, off));
    if ((t & 63) == 0) red[t >> 6] = m;
    __syncthreads();
    m = fmaxf(fmaxf(red[0], red[1]), fmaxf(red[2], red[3]));

    const int bx = blockIdx.x;   // 0..55 interior (hh = bx+1); 56 -> row 0; 57 -> row 57
    const int cc = blockIdx.y;   // 0..3
    const int n  = blockIdx.z;   // 0..31
    if (bx == 0 && cc == 0 && n == 0 && t == 0) *am_bits = __float_as_uint(m);

    int8_t* plane = xq + (size_t)(n * 4 + cc) * XQ_CSTR;
    if (bx >= 56) {              // zero-fill border rows
        const int hh = (bx == 56) ? 0 : 57;
        if (t < 232) *(i32x4*)(plane + (size_t)hh * XQ_WSTR + t * 16) = (i32x4){0, 0, 0, 0};
        return;
    }
    const int hh = bx + 1;
    const int wg = t & 15;
    const int cg = t >> 4;
    int8_t* orow = plane + (size_t)hh * XQ_WSTR;

    if (wg >= 14) {              // zero-fill ww border columns
        const int ww = (wg == 14) ? 0 : 57;
        *(int*)(orow + ww * 64 + cg * 4) = 0;
        return;
    }

    const float scale = 127.f / fmaxf(m, 1e-20f);
    const float* src = x + ((size_t)n * C_IN + cc * 64 + cg * 4) * HW
                         + (size_t)bx * W_IN + wg * 4;
    int8_t qb[4][4];             // [channel j][pixel k]
#pragma unroll
    for (int j = 0; j < 4; ++j) {
        f32x4 v = *(const f32x4*)(src + (size_t)j * HW);
#pragma unroll
        for (int k = 0; k < 4; ++k) {
            float f = v[k] * scale;
            f = fminf(fmaxf(f, -127.f), 127.f);
            qb[j][k] = (int8_t)(int)rintf(f);
        }
    }
#pragma unroll
    for (int k = 0; k < 4; ++k) {
        int d = (int)(uint8_t)qb[0][k] | ((int)(uint8_t)qb[1][k] << 8)
              | ((int)(uint8_t)qb[2][k] << 16) | ((int)(uint8_t)qb[3][k] << 24);
        *(int*)(orow + (wg * 4 + k + 1) * 64 + cg * 4) = d;
    }
}

// ---- main: block = 128 o x 224 px (4 out rows x 56), 3-tap-chunk pipelined K-loop ----
// 1-D grid 896 with XCD-pairing swizzle (dispatcher round-robins workgroup id % 8 -> XCD):
//   oblk partners of one tile are 8 ids apart (same XCD, adjacent in time) and consecutive
//   nrp share an XCD -> xq halo reads become L2 hits for the partner/neighbors.
__launch_bounds__(256, 2)
__global__ void bconv_i8(const int8_t* __restrict__ xq,
                         const int8_t* __restrict__ wq,
                         const float* __restrict__ bias,
                         const unsigned* __restrict__ amax_bits,
                         float* __restrict__ out) {
    __shared__ __attribute__((aligned(16))) int8_t As[2 * CHUNK_B];  // 49152 (DMA dest)
    __shared__ __attribute__((aligned(16))) int8_t Bs[6 * BS_ROWB];  // 27840 B halo

    const int tid  = threadIdx.x;
    const int lane = tid & 63;
    const int wv   = tid >> 6;
    const int row  = lane & 15;
    const int quad = lane >> 4;

    // XCD-pairing swizzle: j in 0..895
    const int j    = blockIdx.x;
    const int rem  = j >> 3;                  // 0..111
    const int oblk = rem & 1;                 // partner ids differ by 8 -> same XCD
    const int nrp  = (j & 7) * 56 + (rem >> 1);   // 0..447, consecutive on one XCD
    const int n    = nrp / 14;
    const int rp   = nrp - n * 14;
    const int h0   = rp * 4;

    int pr[4], pc[4];
    bool live[4];
#pragma unroll
    for (int nt = 0; nt < 4; ++nt) {
        int p = wv * 64 + nt * 16 + row;
        live[nt] = (p < 224);
        int r = p / 56;
        int c = p - r * 56;
        if (!live[nt]) { r = 0; c = 0; }
        pr[nt] = r;
        pc[nt] = c;
    }

    i32x4 acc[8][4];
#pragma unroll
    for (int mt = 0; mt < 8; ++mt)
#pragma unroll
        for (int nt = 0; nt < 4; ++nt)
            acc[mt][nt] = (i32x4){0, 0, 0, 0};

    // A-read lane address: permuted chunk -> conflict-free at pitch 64
    const int rowA = row * 64 + (((quad + (row >> 1)) & 3) << 4);
    int addrB[4];
#pragma unroll
    for (int nt = 0; nt < 4; ++nt)
        addrB[nt] = pr[nt] * BS_ROWB + pc[nt] * BPITCH + quad * 16;

    // DMA chunk c (3 taps = steps 3c..3c+2) into As[c&1]; each wave stages its quarter
    auto issueA3 = [&](int c) {
        const int8_t* g = wq + (size_t)(3 * c) * 16384 + oblk * 8192 + wv * 2048 + lane * 16;
        int8_t* l = &As[(c & 1) * CHUNK_B + wv * 2048];
#pragma unroll
        for (int u = 0; u < 3; ++u) {
            dma16(g + u * 16384,        l + u * 8192);
            dma16(g + u * 16384 + 1024, l + u * 8192 + 1024);
        }
    };

    issueA3(0);   // prologue

    i32x4 af[8], bc[4], bn[4];

    for (int cc = 0; cc < 4; ++cc) {
        __syncthreads();   // closes prev-cc Bs/As readers; drains DMA(chunk cc*3)
        // ---- stage B halo for this cc: 6 rows x 58 cols x 64 ch ----
        if (tid < 232) {
            const int8_t* bbase = xq + (size_t)(n * 4 + cc) * XQ_CSTR
                                     + (size_t)h0 * XQ_WSTR + tid * 16;
            int8_t* ldst = &Bs[(tid >> 2) * BPITCH + (tid & 3) * 16];
            i32x4 hv[6];
#pragma unroll
            for (int r6 = 0; r6 < 6; ++r6)
                hv[r6] = *(const i32x4*)(bbase + r6 * XQ_WSTR);
#pragma unroll
            for (int r6 = 0; r6 < 6; ++r6)
                *(i32x4*)(ldst + r6 * BS_ROWB) = hv[r6];
        }
        __syncthreads();   // Bs visible

#pragma unroll
        for (int k = 0; k < 3; ++k) {
            const int c = cc * 3 + k;
            if (k == 0) {
                if (c + 1 < 12) issueA3(c + 1);     // buf (c+1)&1: its readers closed above
#pragma unroll
                for (int nt = 0; nt < 4; ++nt)      // tap k*3 = offset k*BS_ROWB (k=0)
                    bc[nt] = *(const i32x4*)(&Bs[addrB[nt]]);
            } else {
                __syncthreads();                    // drains DMA(c); closes buf (c+1)&1 readers
                if (c + 1 < 12) issueA3(c + 1);
#pragma unroll
                for (int nt = 0; nt < 4; ++nt) bc[nt] = bn[nt];   // prefetched pre-barrier
            }
            const int8_t* Acur = &As[(c & 1) * CHUNK_B];
#pragma unroll
            for (int mt = 0; mt < 8; ++mt)
                af[mt] = *(const i32x4*)(Acur + mt * 1024 + rowA);

#pragma unroll
            for (int u = 0; u < 3; ++u) {           // taps k*3+u of this cc
                if (u < 2) {
                    const int offn = k * BS_ROWB + (u + 1) * BPITCH;
#pragma unroll
                    for (int nt = 0; nt < 4; ++nt)
                        bn[nt] = *(const i32x4*)(&Bs[addrB[nt] + offn]);
                    const int8_t* Anx = Acur + (u + 1) * 8192;
#pragma unroll
                    for (int mt = 0; mt < 8; ++mt) {
                        i32x4 a = af[mt];
#pragma unroll
                        for (int nt = 0; nt < 4; ++nt)
                            acc[mt][nt] = __builtin_amdgcn_mfma_i32_16x16x64_i8(
                                a, bc[nt], acc[mt][nt], 0, 0, 0);
                        af[mt] = *(const i32x4*)(Anx + mt * 1024 + rowA);  // tap u+1, hidden
                    }
#pragma unroll
                    for (int nt = 0; nt < 4; ++nt) bc[nt] = bn[nt];
                } else {
                    if (k < 2) {                    // prefetch next chunk's tap0 (Bs stable in cc)
                        const int offn = (k + 1) * BS_ROWB;
#pragma unroll
                        for (int nt = 0; nt < 4; ++nt)
                            bn[nt] = *(const i32x4*)(&Bs[addrB[nt] + offn]);
                    }
#pragma unroll
                    for (int mt = 0; mt < 8; ++mt)
#pragma unroll
                        for (int nt = 0; nt < 4; ++nt)
                            acc[mt][nt] = __builtin_amdgcn_mfma_i32_16x16x64_i8(
                                af[mt], bc[nt], acc[mt][nt], 0, 0, 0);
                }
            }
        }
    }

    // ---- epilogue, nt-inner: 4 x 64B consecutive stores per channel (write combining) ----
    const float am  = __uint_as_float(*amax_bits);
    const float inv = am * (1.0f / 127.0f);
    float* base0 = out + ((size_t)n * O_OUT + oblk * 128) * HW;
    int pixoff[4];
#pragma unroll
    for (int nt = 0; nt < 4; ++nt)
        pixoff[nt] = (h0 + pr[nt]) * W_IN + pc[nt];
#pragma unroll
    for (int mt = 0; mt < 8; ++mt) {
        f32x4 bv = *(const f32x4*)(bias + oblk * 128 + mt * 16 + quad * 4);
#pragma unroll
        for (int r = 0; r < 4; ++r) {
            const float sb = (bv[r] >= 0.0f) ? 1.0f : -1.0f;
            const size_t ob = (size_t)(mt * 16 + quad * 4 + r) * HW;
#pragma unroll
            for (int nt = 0; nt < 4; ++nt)
                if (live[nt]) base0[ob + pixoff[nt]] = (float)acc[mt][nt][r] * inv + sb;
        }
    }
}

// ================= fallback (only if ws too small): fp32->bf16 direct =================
#define CHW (C_IN * HW)
#define FPITCH 40

__launch_bounds__(256, 2)
__global__ void bconv_fallback(const float* __restrict__ x,
                               const float* __restrict__ w,
                               const float* __restrict__ bias,
                               float* __restrict__ out) {
    __shared__ __attribute__((aligned(16))) __bf16 Asf[128 * FPITCH];
    __shared__ __attribute__((aligned(16))) __bf16 Bsf[128 * FPITCH];

    const int tid  = threadIdx.x;
    const int lane = tid & 63;
    const int wv   = tid >> 6;
    const int pblk = blockIdx.x;
    const int oblk = blockIdx.y;

    const int p_local = tid & 127;
    const int cgrp    = tid >> 7;
    const int pixel   = pblk * 128 + p_local;
    const int n_img   = pixel / HW;
    const int hw      = pixel - n_img * HW;
    const int h       = hw / W_IN;
    const int wx      = hw - h * W_IN;
    const float* xbase = x + (size_t)n_img * CHW;

    f32x4 acc[8][2];
#pragma unroll
    for (int mt = 0; mt < 8; ++mt)
#pragma unroll
        for (int nt = 0; nt < 2; ++nt)
            acc[mt][nt] = (f32x4){0.f, 0.f, 0.f, 0.f};

    const int pix_wave = wv * 32;
    const int row  = lane & 15;
    const int quad = lane >> 4;

    for (int tap = 0; tap < 9; ++tap) {
        const int dh = tap / 3 - 1;
        const int dw = tap % 3 - 1;
        const int hh = h + dh;
        const int ww = wx + dw;
        const bool valid = ((unsigned)hh < (unsigned)H_IN) && ((unsigned)ww < (unsigned)W_IN);
        const int offs = hh * W_IN + ww;

        for (int ck = 0; ck < 8; ++ck) {
            __syncthreads();
#pragma unroll
            for (int rep = 0; rep < 2; ++rep) {
                int v  = tid + rep * 256;
                int oa = v >> 2;
                int c8 = v & 3;
                const float* wsrc = w + (size_t)(oblk * 128 + oa) * K_RAW
                                      + (ck * 32 + c8 * 8) * 9 + tap;
                bf16x8 val;
#pragma unroll
                for (int j = 0; j < 8; ++j)
                    val[j] = (wsrc[j * 9] >= 0.0f) ? (__bf16)1.0f : (__bf16)(-1.0f);
                *(bf16x8*)(&Asf[oa * FPITCH + c8 * 8]) = val;
            }
            {
                const int cbase = (ck * 32 + cgrp * 16) * HW + offs;
#pragma unroll
                for (int g = 0; g < 2; ++g) {
                    bf16x8 vb;
#pragma unroll
                    for (int j = 0; j < 8; ++j) {
                        float f = valid ? xbase[cbase + (g * 8 + j) * HW] : 0.0f;
                        vb[j] = (__bf16)f;
                    }
                    *(bf16x8*)(&Bsf[p_local * FPITCH + cgrp * 16 + g * 8]) = vb;
                }
            }
            __syncthreads();
            bf16x8 bfrag[2];
#pragma unroll
            for (int nt = 0; nt < 2; ++nt)
                bfrag[nt] = *(const bf16x8*)(&Bsf[(pix_wave + nt * 16 + row) * FPITCH + quad * 8]);
#pragma unroll
            for (int mt = 0; mt < 8; ++mt) {
                bf16x8 afrag = *(const bf16x8*)(&Asf[(mt * 16 + row) * FPITCH + quad * 8]);
#pragma unroll
                for (int nt = 0; nt < 2; ++nt)
                    acc[mt][nt] = __builtin_amdgcn_mfma_f32_16x16x32_bf16(
                        afrag, bfrag[nt], acc[mt][nt], 0, 0, 0);
            }
        }
    }

#pragma unroll
    for (int nt = 0; nt < 2; ++nt) {
        int pix = pblk * 128 + pix_wave + nt * 16 + row;
        int ni  = pix / HW;
        int phw = pix - ni * HW;
        float* obase = out + (size_t)ni * (O_OUT * HW) + phw;
#pragma unroll
        for (int mt = 0; mt < 8; ++mt) {
            int o0 = oblk * 128 + mt * 16 + quad * 4;
#pragma unroll
            for (int r = 0; r < 4; ++r) {
                int o = o0 + r;
                float sb = (bias[o] >= 0.0f) ? 1.0f : -1.0f;
                obase[(size_t)o * HW] = acc[mt][nt][r] + sb;
            }
        }
    }
}

extern "C" void kernel_launch(void* const* d_in, const int* in_sizes, int n_in,
                              void* d_out, int out_size, void* d_ws, size_t ws_size,
                              hipStream_t stream) {
    const float* x    = (const float*)d_in[0];
    const float* w    = (const float*)d_in[1];
    const float* bias = (const float*)d_in[2];
    float* out        = (float*)d_out;

    if (ws_size >= WS_NEED) {
        int8_t*   xq     = (int8_t*)d_ws;
        int8_t*   wq     = (int8_t*)d_ws + XQ_BYTES;
        unsigned* am     = (unsigned*)((char*)d_ws + AM_OFF);
        float*    am_arr = (float*)((char*)d_ws + ARR_OFF);

        prep_combo<<<dim3(16 + AMAX_BLOCKS), dim3(256), 0, stream>>>(x, w, wq, am_arr);
        xtrans_q<<<dim3(58, 4, N_IMG), dim3(256), 0, stream>>>(x, xq, am_arr, am);
        bconv_i8<<<dim3(896), dim3(256), 0, stream>>>(xq, wq, bias, am, out);
    } else {
        bconv_fallback<<<dim3((N_IMG * HW) / 128, 2), dim3(256), 0, stream>>>(
            x, w, bias, out);
    }
}